// Round 7
// baseline (1795.986 us; speedup 1.0000x reference)
//
#include <hip/hip_runtime.h>
#include <hip/hip_bf16.h>
#include <cmath>
#include <cstdint>

#define NPT 4095      // nodes per tree
#define NT  32760     // total nodes (8 trees)
#define FD  512       // hidden/feature dim

using bf16 = __hip_bfloat16;
using bf8v = __attribute__((ext_vector_type(8))) short;   // 8 bf16 (4 VGPRs)
using us8v = __attribute__((ext_vector_type(8))) unsigned short;
using f4v  = __attribute__((ext_vector_type(4))) float;   // MFMA accumulator

__device__ __forceinline__ float b2f(bf16 x){ return __bfloat162float(x); }
__device__ __forceinline__ bf16  f2b(float x){ return __float2bfloat16(x); }
__device__ __forceinline__ float us2f(unsigned short u){ union{unsigned int i; float f;} v; v.i = ((unsigned)u)<<16; return v.f; }
__device__ __forceinline__ unsigned short f2us(float f){ union{bf16 b; unsigned short u;} v; v.b = __float2bfloat16(f); return v.u; }

// fast transcendentals: v_exp_f32 + v_rcp_f32 (~1 ulp each; bf16 outputs don't care)
__device__ __forceinline__ float fast_sig(float x){
  float e = __builtin_amdgcn_exp2f(-1.4426950408889634f * x);
  return __builtin_amdgcn_rcpf(1.f + e);
}
__device__ __forceinline__ float fast_tanh(float x){
  float ax = fabsf(x);
  float e = __builtin_amdgcn_exp2f(-2.885390081777927f * ax);
  float r = (1.f - e) * __builtin_amdgcn_rcpf(1.f + e);
  return copysignf(r, x);
}

// async 16B global -> LDS (dest = wave-uniform base + lane*16)
__device__ __forceinline__ void gload_lds16(const bf16* g, bf16* l){
  __builtin_amdgcn_global_load_lds(
    (const __attribute__((address_space(1))) unsigned int*)g,
    (__attribute__((address_space(3))) unsigned int*)l, 16, 0, 0);
}

// ---------------- staging kernels ----------------

__global__ void cvt_b16(bf16* __restrict__ dst, const float* __restrict__ src, int n8){
  int e = blockIdx.x*256 + threadIdx.x;
  if (e >= n8) return;
  const float4* s = (const float4*)(src + (size_t)e*8);
  float4 a = s[0], b = s[1];
  us8v o = { f2us(a.x), f2us(a.y), f2us(a.z), f2us(a.w),
             f2us(b.x), f2us(b.y), f2us(b.z), f2us(b.w) };
  *(us8v*)(dst + (size_t)e*8) = o;
}

struct PackArgs { const float* s[16]; bf16* d[16]; int dk[16]; int ro[16]; int co[16]; };
__global__ void pack_all(PackArgs pa){
  int idx = blockIdx.x >> 7;               // 128 blocks per 512x512 matrix
  int e = (blockIdx.x & 127)*256 + threadIdx.x;   // 32768 8-elem chunks
  int r = e >> 6, c8 = e & 63;
  const float4* s = (const float4*)(pa.s[idx] + (size_t)r*512 + c8*8);
  float4 a = s[0], b = s[1];
  us8v o = { f2us(a.x), f2us(a.y), f2us(a.z), f2us(a.w),
             f2us(b.x), f2us(b.y), f2us(b.z), f2us(b.w) };
  *(us8v*)(pa.d[idx] + (size_t)(pa.ro[idx] + r)*pa.dk[idx] + pa.co[idx] + c8*8) = o;
}

// roots: hd[root]=h[root]; sA[2t]=sA[2t+1]=h[root]
__global__ void roots_k(bf16* __restrict__ hd, bf16* __restrict__ sA, const bf16* __restrict__ h){
  int e = blockIdx.x*256 + threadIdx.x;    // 512
  int t = e >> 6, c8 = e & 63;
  size_t off = ((size_t)t*NPT + 4094)*FD + c8*8;
  us8v v = *(const us8v*)(h + off);
  *(us8v*)(hd + off) = v;
  *(us8v*)(sA + (size_t)(2*t)*FD + c8*8) = v;
  *(us8v*)(sA + (size_t)(2*t+1)*FD + c8*8) = v;
}

// ---------------- fused small-level kernel (M <= 1024) ----------------
// One dispatch = gates + cand for a whole tree level.
// grid (ceil(M/64), 8); block 256. Each block owns 64 rows x 64 cand-cols.
// Phase A: z tile (regs, same fragment mapping as cand -> elementwise aligned).
// Phase B: rh row-strip 64x512 computed redundantly per block, stored to LDS
//          (chunk-swizzled: chunk c of row r at slot c^(r&7), same as As).
// Phase C: cand K=1024 (k<512 from featb tree rows; k>=512 from rh LDS).
__global__ __launch_bounds__(256) void level_fused(
    const bf16* __restrict__ sCur, const bf16* __restrict__ featb,
    const bf16* __restrict__ Uzr, const bf16* __restrict__ Whu,
    const float* __restrict__ bz, const float* __restrict__ br,
    const bf16* __restrict__ xw,
    bf16* __restrict__ hO, bf16* __restrict__ sN,
    int M, int o_start, int o_log2, int smode)
{
  __shared__ bf16 rhL[64*512];     // 64 KB
  const int t = threadIdx.x, lane = t & 63, wid = t >> 6;
  const int lr = lane & 15, quad = lane >> 4;
  const int wr = wid >> 1, wc = wid & 1;
  const int m_base = blockIdx.x*64;
  const int n_base = blockIdx.y*64;
  const int Mm1 = M - 1;
  const int omask = (1 << o_log2) - 1;

  // ---- phase A: z tile (64 x 64 @ n_base), K=512, A = sCur direct rows ----
  f4v zac[2][2] = {};
  {
    const bf16 *ap[2], *bp[2];
    #pragma unroll
    for (int mt = 0; mt < 2; ++mt){
      int m = m_base + wr*32 + mt*16 + lr; if (m > Mm1) m = Mm1;
      ap[mt] = sCur + (size_t)m*FD + quad*8;
    }
    #pragma unroll
    for (int nt = 0; nt < 2; ++nt)
      bp[nt] = Uzr + (size_t)(n_base + wc*32 + nt*16 + lr)*512 + quad*8;
    #pragma unroll 4
    for (int k0 = 0; k0 < 512; k0 += 32){
      bf8v a[2], b[2];
      a[0] = *(const bf8v*)(ap[0] + k0); a[1] = *(const bf8v*)(ap[1] + k0);
      b[0] = *(const bf8v*)(bp[0] + k0); b[1] = *(const bf8v*)(bp[1] + k0);
      #pragma unroll
      for (int mt = 0; mt < 2; ++mt)
        #pragma unroll
        for (int nt = 0; nt < 2; ++nt)
          zac[mt][nt] = __builtin_amdgcn_mfma_f32_16x16x32_bf16(a[mt], b[nt], zac[mt][nt], 0, 0, 0);
    }
  }
  // activate z in place (kept in regs; same elem mapping as cand acc)
  f4v zv[2][2];
  #pragma unroll
  for (int mt = 0; mt < 2; ++mt){
    int rbase = m_base + wr*32 + mt*16 + quad*4;
    #pragma unroll
    for (int nt = 0; nt < 2; ++nt){
      int n = n_base + wc*32 + nt*16 + lr;
      #pragma unroll
      for (int i = 0; i < 4; ++i){
        int row = rbase + i; if (row > Mm1) row = Mm1;
        size_t node = (size_t)(row >> o_log2)*NPT + o_start + (row & omask);
        zv[mt][nt][i] = fast_sig(zac[mt][nt][i] + b2f(xw[node*1024 + n]) + bz[n]);
      }
    }
  }

  // ---- phase B: rh strip 64 x 512; wave wid covers cols wid*128..+127 ----
  for (int cc = 0; cc < 2; ++cc){
    int colb = wid*128 + cc*64;
    f4v rac[4][4] = {};
    const bf16 *ap[4], *bp[4];
    #pragma unroll
    for (int mt = 0; mt < 4; ++mt){
      int m = m_base + mt*16 + lr; if (m > Mm1) m = Mm1;
      ap[mt] = sCur + (size_t)m*FD + quad*8;
    }
    #pragma unroll
    for (int nt = 0; nt < 4; ++nt)
      bp[nt] = Uzr + (size_t)(512 + colb + nt*16 + lr)*512 + quad*8;
    #pragma unroll 2
    for (int k0 = 0; k0 < 512; k0 += 32){
      bf8v a[4], b[4];
      #pragma unroll
      for (int mt = 0; mt < 4; ++mt) a[mt] = *(const bf8v*)(ap[mt] + k0);
      #pragma unroll
      for (int nt = 0; nt < 4; ++nt) b[nt] = *(const bf8v*)(bp[nt] + k0);
      #pragma unroll
      for (int mt = 0; mt < 4; ++mt)
        #pragma unroll
        for (int nt = 0; nt < 4; ++nt)
          rac[mt][nt] = __builtin_amdgcn_mfma_f32_16x16x32_bf16(a[mt], b[nt], rac[mt][nt], 0, 0, 0);
    }
    // rh = sig(acc + xw_r + br) * s  -> LDS (swizzled chunks)
    #pragma unroll
    for (int mt = 0; mt < 4; ++mt){
      int rl0 = mt*16 + quad*4;
      #pragma unroll
      for (int nt = 0; nt < 4; ++nt){
        int col = colb + nt*16 + lr;
        #pragma unroll
        for (int i = 0; i < 4; ++i){
          int rl = rl0 + i;
          int row = m_base + rl; if (row > Mm1) row = Mm1;
          size_t node = (size_t)(row >> o_log2)*NPT + o_start + (row & omask);
          float r = fast_sig(rac[mt][nt][i] + b2f(xw[node*1024 + 512 + col]) + br[col]);
          float sv = b2f(sCur[(size_t)row*FD + col]);
          int slot = (col >> 3) ^ (rl & 7);
          rhL[rl*512 + slot*8 + (col & 7)] = f2b(r * sv);
        }
      }
    }
  }
  __syncthreads();

  // ---- phase C: cand tile 64x64 (same mapping as z), K=1024 ----
  f4v cac[2][2] = {};
  {
    const bf16 *ap[2], *bp[2];
    int rla[2];
    #pragma unroll
    for (int mt = 0; mt < 2; ++mt){
      int rl = wr*32 + mt*16 + lr;
      rla[mt] = rl;
      int m = m_base + rl; if (m > Mm1) m = Mm1;
      size_t node = (size_t)(m >> o_log2)*NPT + o_start + (m & omask);
      ap[mt] = featb + node*FD + quad*8;
    }
    #pragma unroll
    for (int nt = 0; nt < 2; ++nt)
      bp[nt] = Whu + (size_t)(n_base + wc*32 + nt*16 + lr)*1024 + quad*8;
    #pragma unroll 4
    for (int k0 = 0; k0 < 512; k0 += 32){
      bf8v a[2], b[2];
      a[0] = *(const bf8v*)(ap[0] + k0); a[1] = *(const bf8v*)(ap[1] + k0);
      b[0] = *(const bf8v*)(bp[0] + k0); b[1] = *(const bf8v*)(bp[1] + k0);
      #pragma unroll
      for (int mt = 0; mt < 2; ++mt)
        #pragma unroll
        for (int nt = 0; nt < 2; ++nt)
          cac[mt][nt] = __builtin_amdgcn_mfma_f32_16x16x32_bf16(a[mt], b[nt], cac[mt][nt], 0, 0, 0);
    }
    #pragma unroll 4
    for (int k0 = 512; k0 < 1024; k0 += 32){
      int chunk = ((k0 - 512) >> 3) + quad;
      bf8v a[2], b[2];
      #pragma unroll
      for (int mt = 0; mt < 2; ++mt){
        int slot = chunk ^ (rla[mt] & 7);
        a[mt] = *(const bf8v*)&rhL[rla[mt]*512 + slot*8];
      }
      b[0] = *(const bf8v*)(bp[0] + k0); b[1] = *(const bf8v*)(bp[1] + k0);
      #pragma unroll
      for (int mt = 0; mt < 2; ++mt)
        #pragma unroll
        for (int nt = 0; nt < 2; ++nt)
          cac[mt][nt] = __builtin_amdgcn_mfma_f32_16x16x32_bf16(a[mt], b[nt], cac[mt][nt], 0, 0, 0);
    }
  }

  // ---- epilogue: h = z*s + (1-z)*tanh(c) ----
  #pragma unroll
  for (int mt = 0; mt < 2; ++mt){
    int rbase = m_base + wr*32 + mt*16 + quad*4;
    if (rbase >= M) continue;
    #pragma unroll
    for (int nt = 0; nt < 2; ++nt){
      int n = n_base + wc*32 + nt*16 + lr;
      float hv[4];
      #pragma unroll
      for (int i = 0; i < 4; ++i){
        int row = rbase + i;
        if (row >= M){ hv[i] = 0.f; continue; }
        float c = fast_tanh(cac[mt][nt][i]);
        float z = zv[mt][nt][i];
        float s = b2f(sCur[(size_t)row*FD + n]);
        float h = z*s + (1.f - z)*c;
        hv[i] = h;
        size_t node = (size_t)(row >> o_log2)*NPT + o_start + (row & omask);
        hO[node*FD + n] = f2b(h);
      }
      if (smode == 1){
        if (rbase + 1 < M) sN[(size_t)(rbase>>1)*FD + n] = f2b(hv[0] + hv[1]);
        if (rbase + 3 < M) sN[(size_t)((rbase>>1)+1)*FD + n] = f2b(hv[2] + hv[3]);
      } else if (smode == 2){
        #pragma unroll
        for (int i = 0; i < 4; ++i){
          int row = rbase + i; if (row >= M) break;
          bf16 hb = f2b(hv[i]);
          sN[(size_t)(2*row)*FD + n] = hb;
          sN[(size_t)(2*row+1)*FD + n] = hb;
        }
      }
    }
  }
}

// ---------------- big GEMM: 128x128 tile, BK=64, swizzled LDS ----------------
// modes: 1 gates; 2 cand; 3 precompute (N=1024 raw bf16); 4 out (f32 + biases);
//        5 fused leaf (h=(1-sig(xw))*tanh(v); pair-sum -> sN)
#define CPAD 132
__global__ __launch_bounds__(256) void gemm_big(
    const bf16* __restrict__ A0, const bf16* __restrict__ A1,
    const bf16* __restrict__ Wp, int M, int K, int ldb,
    int a_start, int a_log2, int o_start, int o_log2,
    const float* __restrict__ bias0, const float* __restrict__ bias1,
    const bf16* __restrict__ zb, const bf16* __restrict__ sb,
    const bf16* __restrict__ xw,
    bf16* __restrict__ o0, bf16* __restrict__ o1,
    bf16* __restrict__ hO, float* __restrict__ outF,
    bf16* __restrict__ sN, int smode, int mode)
{
  __shared__ __align__(16) char smemraw[64*CPAD*4];   // 33.8KB: staging (32KB) U half-C f32
  bf16* As = (bf16*)smemraw;
  bf16* Bs = As + 128*64;
  float* Cf = (float*)smemraw;

  const int t = threadIdx.x, lane = t & 63, wid = t >> 6;
  const int wr = wid >> 1, wc = wid & 1;
  const int lr = lane & 15, quad = lane >> 4;

  // XCD-aware bijective swizzle; n_blk fastest within a chunk so the 8 blocks
  // sharing an A-panel are temporally adjacent on ONE XCD (A-panel L2-resident).
  const int gx = gridDim.x, gy = gridDim.y;
  int nwg = gx * gy;
  int id = blockIdx.y * gx + blockIdx.x;
  int q = nwg >> 3, r8 = nwg & 7;
  int xcd = id & 7, jj = id >> 3;
  int wg = (xcd < r8 ? xcd*(q+1) : r8*(q+1) + (xcd - r8)*q) + jj;
  const int m_blk = (wg / gy) * 128, n_blk = (wg % gy) * 128;

  const int Mm1 = M - 1;
  const int amask = (1 << a_log2) - 1;
  const int wbase = (t & ~63);

  // hoisted per-thread staging sources (chunk g stored at slot g^(row&7))
  const bf16* a0p[4]; const bf16* a1p[4]; const bf16* bp[4];
  #pragma unroll
  for (int p = 0; p < 4; ++p){
    int c = p*256 + t;
    int rl = c >> 3, slot = c & 7;
    int g = slot ^ (rl & 7);
    int r = m_blk + rl; if (r > Mm1) r = Mm1;
    int tr = r >> a_log2, po = r & amask;
    a0p[p] = A0 + ((size_t)tr*NPT + a_start + po)*FD + g*8;
    a1p[p] = A1 + (size_t)r*FD + g*8;
    bp[p]  = Wp + (size_t)(n_blk + rl)*ldb + g*8;
  }

  f4v acc[4][4] = {};

  for (int k0 = 0; k0 < K; k0 += 64){
    #pragma unroll
    for (int p = 0; p < 4; ++p){
      const bf16* src = (k0 < 512) ? (a0p[p] + k0) : (a1p[p] + (k0 - 512));
      gload_lds16(src, &As[(size_t)(p*256 + wbase)*8]);
    }
    #pragma unroll
    for (int p = 0; p < 4; ++p)
      gload_lds16(bp[p] + k0, &Bs[(size_t)(p*256 + wbase)*8]);
    __syncthreads();

    #pragma unroll
    for (int kh = 0; kh < 2; ++kh){
      int cidx = kh*4 + quad;
      bf8v af[4], bv[4];
      #pragma unroll
      for (int i = 0; i < 4; ++i){
        int ra = wr*64 + i*16 + lr;
        af[i] = *(const bf8v*)&As[ra*64 + ((cidx ^ (ra & 7))*8)];
        int rb = wc*64 + i*16 + lr;
        bv[i] = *(const bf8v*)&Bs[rb*64 + ((cidx ^ (rb & 7))*8)];
      }
      #pragma unroll
      for (int i = 0; i < 4; ++i)
        #pragma unroll
        for (int j = 0; j < 4; ++j)
          acc[i][j] = __builtin_amdgcn_mfma_f32_16x16x32_bf16(af[i], bv[j], acc[i][j], 0, 0, 0);
    }
    __syncthreads();
  }

  const int omask = (1 << o_log2) - 1;
  const int L0 = (t >> 4) * 4;          // local row base in the 64-row half-tile
  const int c0l = (t & 15) * 8;
  const int n0 = n_blk + c0l;
  const int grb0 = m_blk + (L0 >> 5)*64 + (L0 & 31);   // + p*32 per pass

  #define LOADV(i, vv) { float4 _v0 = *(const float4*)&Cf[(L0+(i))*CPAD + c0l]; \
                         float4 _v1 = *(const float4*)&Cf[(L0+(i))*CPAD + c0l + 4]; \
                         vv[0]=_v0.x; vv[1]=_v0.y; vv[2]=_v0.z; vv[3]=_v0.w; \
                         vv[4]=_v1.x; vv[5]=_v1.y; vv[6]=_v1.z; vv[7]=_v1.w; }

  #pragma unroll
  for (int p = 0; p < 2; ++p){
    __syncthreads();   // protect staging (p=0) / previous pass reads (p=1)
    #pragma unroll
    for (int mt2 = 0; mt2 < 2; ++mt2){
      int lrow = wr*32 + mt2*16 + quad*4;
      #pragma unroll
      for (int nt = 0; nt < 4; ++nt){
        int c = wc*64 + nt*16 + lr;
        #pragma unroll
        for (int i = 0; i < 4; ++i)
          Cf[(lrow+i)*CPAD + c] = acc[2*p+mt2][nt][i];
      }
    }
    __syncthreads();

    const int gr = grb0 + p*32;

    if (mode == 3){
      #pragma unroll
      for (int i = 0; i < 4; ++i){
        int row = gr + i; if (row >= M) continue;
        float vv[8]; LOADV(i, vv);
        us8v o;
        #pragma unroll
        for (int k2 = 0; k2 < 8; ++k2) o[k2] = f2us(vv[k2]);
        *(us8v*)(o0 + (size_t)row*1024 + n0) = o;
      }
    } else if (mode == 4){
      float bb[8];
      *(float4*)&bb[0] = *(const float4*)&bias0[n0];
      *(float4*)&bb[4] = *(const float4*)&bias0[n0+4];
      float b2v[8];
      *(float4*)&b2v[0] = *(const float4*)&bias1[n0];
      *(float4*)&b2v[4] = *(const float4*)&bias1[n0+4];
      #pragma unroll
      for (int k2 = 0; k2 < 8; ++k2) bb[k2] += b2v[k2];
      #pragma unroll
      for (int i = 0; i < 4; ++i){
        int row = gr + i; if (row >= M) continue;
        float vv[8]; LOADV(i, vv);
        float4 o0v = { vv[0]+bb[0], vv[1]+bb[1], vv[2]+bb[2], vv[3]+bb[3] };
        float4 o1v = { vv[4]+bb[4], vv[5]+bb[5], vv[6]+bb[6], vv[7]+bb[7] };
        *(float4*)(outF + (size_t)row*FD + n0)     = o0v;
        *(float4*)(outF + (size_t)row*FD + n0 + 4) = o1v;
      }
    } else if (mode == 1){
      if (n0 < 512){
        float bb[8];
        *(float4*)&bb[0] = *(const float4*)&bias0[n0];
        *(float4*)&bb[4] = *(const float4*)&bias0[n0+4];
        #pragma unroll
        for (int i = 0; i < 4; ++i){
          int row = gr + i; if (row >= M) continue;
          size_t node = (size_t)(row >> o_log2)*NPT + o_start + (row & omask);
          us8v xv = *(const us8v*)(xw + node*1024 + n0);
          float vv[8]; LOADV(i, vv);
          us8v o;
          #pragma unroll
          for (int k2 = 0; k2 < 8; ++k2)
            o[k2] = f2us(fast_sig(vv[k2] + us2f(xv[k2]) + bb[k2]));
          *(us8v*)(o0 + (size_t)row*FD + n0) = o;
        }
      } else {
        int n5 = n0 - 512;
        float bb[8];
        *(float4*)&bb[0] = *(const float4*)&bias1[n5];
        *(float4*)&bb[4] = *(const float4*)&bias1[n5+4];
        #pragma unroll
        for (int i = 0; i < 4; ++i){
          int row = gr + i; if (row >= M) continue;
          size_t node = (size_t)(row >> o_log2)*NPT + o_start + (row & omask);
          us8v xv = *(const us8v*)(xw + node*1024 + n0);
          us8v sv = *(const us8v*)(sb + (size_t)row*FD + n5);
          float vv[8]; LOADV(i, vv);
          us8v o;
          #pragma unroll
          for (int k2 = 0; k2 < 8; ++k2){
            float r = fast_sig(vv[k2] + us2f(xv[k2]) + bb[k2]);
            o[k2] = f2us(r * us2f(sv[k2]));
          }
          *(us8v*)(o1 + (size_t)row*FD + n5) = o;
        }
      }
    } else if (mode == 5){   // fused leaf
      float hprev[8];
      #pragma unroll
      for (int i = 0; i < 4; ++i){
        int row = gr + i; if (row >= M) continue;
        size_t node = (size_t)(row >> o_log2)*NPT + o_start + (row & omask);
        us8v zv = *(const us8v*)(xw + node*1024 + n0);
        float vv[8]; LOADV(i, vv);
        float hc[8]; us8v hb;
        #pragma unroll
        for (int k2 = 0; k2 < 8; ++k2){
          float h = (1.f - fast_sig(us2f(zv[k2]))) * fast_tanh(vv[k2]);
          hc[k2] = h; hb[k2] = f2us(h);
        }
        *(us8v*)(hO + node*FD + n0) = hb;
        if (i & 1){
          us8v ss;
          #pragma unroll
          for (int k2 = 0; k2 < 8; ++k2) ss[k2] = f2us(hprev[k2] + hc[k2]);
          *(us8v*)(sN + (size_t)(row>>1)*FD + n0) = ss;
        } else {
          #pragma unroll
          for (int k2 = 0; k2 < 8; ++k2) hprev[k2] = hc[k2];
        }
      }
    } else {   // mode 2: cand
      float hprev[8];
      #pragma unroll
      for (int i = 0; i < 4; ++i){
        int row = gr + i; if (row >= M) continue;
        us8v zv = *(const us8v*)(zb + (size_t)row*FD + n0);
        us8v sv = *(const us8v*)(sb + (size_t)row*FD + n0);
        float vv[8]; LOADV(i, vv);
        float hc[8]; us8v hb;
        #pragma unroll
        for (int k2 = 0; k2 < 8; ++k2){
          float c = fast_tanh(vv[k2]);
          float z = us2f(zv[k2]);
          float s = us2f(sv[k2]);
          float h = z*s + (1.f - z)*c;
          hc[k2] = h; hb[k2] = f2us(h);
        }
        size_t node = (size_t)(row >> o_log2)*NPT + o_start + (row & omask);
        *(us8v*)(hO + node*FD + n0) = hb;
        if (smode == 1){
          if (i & 1){
            us8v ss;
            #pragma unroll
            for (int k2 = 0; k2 < 8; ++k2) ss[k2] = f2us(hprev[k2] + hc[k2]);
            *(us8v*)(sN + (size_t)(row>>1)*FD + n0) = ss;
          } else {
            #pragma unroll
            for (int k2 = 0; k2 < 8; ++k2) hprev[k2] = hc[k2];
          }
        } else if (smode == 2){
          *(us8v*)(sN + (size_t)(2*row)*FD + n0) = hb;
          *(us8v*)(sN + (size_t)(2*row+1)*FD + n0) = hb;
        }
      }
    }
  }
  #undef LOADV
}

// ---------------- host launcher ----------------

extern "C" void kernel_launch(void* const* d_in, const int* in_sizes, int n_in,
                              void* d_out, int out_size, void* d_ws, size_t ws_size,
                              hipStream_t stream)
{
  const float* feat = (const float*)d_in[0];
  const float* Wh   = (const float*)d_in[1];
  const float* Wz   = (const float*)d_in[2];
  const float* Wr   = (const float*)d_in[3];
  const float* Uh   = (const float*)d_in[4];
  const float* Uz   = (const float*)d_in[5];
  const float* bUz  = (const float*)d_in[6];
  const float* Ur   = (const float*)d_in[7];
  const float* bUr  = (const float*)d_in[8];
  const float* Whd  = (const float*)d_in[9];
  const float* Wzd  = (const float*)d_in[10];
  const float* Wrd  = (const float*)d_in[11];
  const float* Uhd  = (const float*)d_in[12];
  const float* Uzd  = (const float*)d_in[13];
  const float* bUzd = (const float*)d_in[14];
  const float* Urd  = (const float*)d_in[15];
  const float* bUrd = (const float*)d_in[16];
  const float* W1   = (const float*)d_in[17];
  const float* b1   = (const float*)d_in[18];
  const float* W2   = (const float*)d_in[19];
  const float* b2   = (const float*)d_in[20];
  float* out = (float*)d_out;

  int starts[12], szs[12];
  { int s = 0, sz = 2048; for (int l = 0; l < 12; ++l){ starts[l] = s; szs[l] = sz; s += sz; sz >>= 1; } }

  char* p = (char*)d_ws;
  auto take = [&](size_t b)->char*{ char* q = p; p += (b + 255) & ~(size_t)255; return q; };
  bf16* featb = (bf16*)take((size_t)NT*FD*2);
  bf16* h_b   = (bf16*)take((size_t)NT*FD*2);
  bf16* hd_b  = (bf16*)take((size_t)NT*FD*2);
  bf16* Wzr_u = (bf16*)take((size_t)1024*512*2);
  bf16* Wzr_d = (bf16*)take((size_t)1024*512*2);
  bf16* Uzr_u = (bf16*)take((size_t)1024*512*2);
  bf16* Uzr_d = (bf16*)take((size_t)1024*512*2);
  bf16* Whu   = (bf16*)take((size_t)512*1024*2);
  bf16* Whu_d = (bf16*)take((size_t)512*1024*2);
  bf16* Wout  = (bf16*)take((size_t)512*1024*2);
  bf16* z16   = (bf16*)take((size_t)16384*512*2);
  bf16* rh16  = (bf16*)take((size_t)16384*512*2);
  bf16* sP0   = (bf16*)take((size_t)16384*512*2);
  bf16* sP1   = (bf16*)take((size_t)16384*512*2);
  if ((size_t)(p - (char*)d_ws) > ws_size) return;

  // xWzr = per-node x@[Wz|Wr] (NT x 1024 bf16) lives in d_out as scratch
  bf16* xWzr = (bf16*)d_out;

  // --- stage inputs: 2 launches ---
  cvt_b16<<<(NT*FD/8 + 255)/256, 256, 0, stream>>>(featb, feat, NT*FD/8);
  PackArgs pa;
  int pi = 0;
  auto pk = [&](const float* src, bf16* dst, int dk, int ro, int co){
    pa.s[pi] = src; pa.d[pi] = dst; pa.dk[pi] = dk; pa.ro[pi] = ro; pa.co[pi] = co; ++pi;
  };
  pk(Wz, Wzr_u, 512, 0, 0);    pk(Wr, Wzr_u, 512, 512, 0);
  pk(Wzd, Wzr_d, 512, 0, 0);   pk(Wrd, Wzr_d, 512, 512, 0);
  pk(Uz, Uzr_u, 512, 0, 0);    pk(Ur, Uzr_u, 512, 512, 0);
  pk(Uzd, Uzr_d, 512, 0, 0);   pk(Urd, Uzr_d, 512, 512, 0);
  pk(Wh, Whu, 1024, 0, 0);     pk(Uh, Whu, 1024, 0, 512);
  pk(Whd, Whu_d, 1024, 0, 0);  pk(Uhd, Whu_d, 1024, 0, 512);
  pk(W1, Wout, 1024, 0, 0);    pk(W2, Wout, 1024, 0, 512);
  pack_all<<<14*128, 256, 0, stream>>>(pa);

  auto gemm = [&](const bf16* A0, const bf16* A1, const bf16* Wp, int M, int N, int K, int ldb,
                  int a_start, int a_log2, int o_start, int o_log2,
                  const float* bias0, const float* bias1,
                  const bf16* zb, const bf16* sb, const bf16* xw,
                  bf16* o0, bf16* o1, bf16* hO, float* outF,
                  bf16* sN, int smode, int mode){
    dim3 g((M + 127)/128, N/128);
    gemm_big<<<g, 256, 0, stream>>>(A0, A1, Wp, M, K, ldb, a_start, a_log2, o_start, o_log2,
                                    bias0, bias1, zb, sb, xw, o0, o1, hO, outF, sN, smode, mode);
  };

  // --- precompute-up: xWzr[node] = x@[Wz|Wr] for ALL nodes ---
  gemm(featb, featb, Wzr_u, NT, 1024, 512, 512, 0, 26, 0, 26,
       nullptr, nullptr, nullptr, nullptr, nullptr, xWzr, nullptr, nullptr, nullptr, nullptr, 0, 3);

  // --- leaves fused: h = (1-sig(xWzr_z))*tanh(x@Wh); pair-sum -> sP0 (mode 5) ---
  gemm(featb, featb, Whu, 16384, 512, 512, 1024, 0, 11, 0, 11,
       nullptr, nullptr, nullptr, nullptr, xWzr, nullptr, nullptr, h_b, nullptr, sP0, 1, 5);

  // --- bottom-up: big levels 2-dispatch; small levels (M<=1024) single fused dispatch ---
  for (int l = 0; l < 11; ++l){
    int Mf = 8*szs[l+1];
    int al2 = 10 - l, os = starts[l+1];
    bf16* sCur = (l & 1) ? sP1 : sP0;
    bf16* sNext = (l & 1) ? sP0 : sP1;
    int smode = (l < 10) ? 1 : 0;
    if (Mf >= 2048){
      gemm(sCur, sCur, Uzr_u, Mf, 1024, 512, 512, 0, 26, os, al2,
           bUz, bUr, nullptr, sCur, xWzr, z16, rh16, nullptr, nullptr, nullptr, 0, 1);
      gemm(featb, rh16, Whu, Mf, 512, 1024, 1024, os, al2, os, al2,
           nullptr, nullptr, z16, sCur, nullptr, nullptr, nullptr, h_b, nullptr, sNext, smode, 2);
    } else {
      dim3 g((Mf + 63)/64, 8);
      level_fused<<<g, 256, 0, stream>>>(sCur, featb, Uzr_u, Whu, bUz, bUr, xWzr,
                                         h_b, sNext, Mf, os, al2, smode);
    }
  }

  // --- precompute-down: xWzr[node] = x@[Wzd|Wrd] ---
  gemm(featb, featb, Wzr_d, NT, 1024, 512, 512, 0, 26, 0, 26,
       nullptr, nullptr, nullptr, nullptr, nullptr, xWzr, nullptr, nullptr, nullptr, nullptr, 0, 3);

  // --- roots ---
  roots_k<<<2, 256, 0, stream>>>(hd_b, sP0, h_b);

  // --- top-down ---
  for (int l = 10; l >= 0; --l){
    int Ms = 8*szs[l];
    int al2 = 11 - l, os = starts[l];
    bf16* sCur = ((10 - l) & 1) ? sP1 : sP0;
    bf16* sNext = ((10 - l) & 1) ? sP0 : sP1;
    int smode = (l > 0) ? 2 : 0;
    if (Ms >= 2048){
      gemm(sCur, sCur, Uzr_d, Ms, 1024, 512, 512, 0, 26, os, al2,
           bUzd, bUrd, nullptr, sCur, xWzr, z16, rh16, nullptr, nullptr, nullptr, 0, 1);
      gemm(featb, rh16, Whu_d, Ms, 512, 1024, 1024, os, al2, os, al2,
           nullptr, nullptr, z16, sCur, nullptr, nullptr, nullptr, hd_b, nullptr, sNext, smode, 2);
    } else {
      dim3 g((Ms + 63)/64, 8);
      level_fused<<<g, 256, 0, stream>>>(sCur, featb, Uzr_d, Whu_d, bUzd, bUrd, xWzr,
                                         hd_b, sNext, Ms, os, al2, smode);
    }
  }

  // --- output: [h|hd] @ [W1|W2].T + b1 + b2 ---
  gemm(h_b, hd_b, Wout, NT, 512, 1024, 1024, 0, 26, 0, 26,
       b1, b2, nullptr, nullptr, nullptr, nullptr, nullptr, nullptr, out, nullptr, 0, 4);
}

// Round 10
// 1434.008 us; speedup vs baseline: 1.2524x; 1.2524x over previous
//
#include <hip/hip_runtime.h>
#include <hip/hip_bf16.h>
#include <cmath>
#include <cstdint>

#define NPT 4095      // nodes per tree
#define NT  32760     // total nodes (8 trees)
#define FD  512       // hidden/feature dim

using bf16 = __hip_bfloat16;
using bf8v = __attribute__((ext_vector_type(8))) short;   // 8 bf16 (4 VGPRs)
using us8v = __attribute__((ext_vector_type(8))) unsigned short;
using f4v  = __attribute__((ext_vector_type(4))) float;   // MFMA accumulator

__device__ __forceinline__ float b2f(bf16 x){ return __bfloat162float(x); }
__device__ __forceinline__ bf16  f2b(float x){ return __float2bfloat16(x); }
__device__ __forceinline__ float us2f(unsigned short u){ union{unsigned int i; float f;} v; v.i = ((unsigned)u)<<16; return v.f; }
__device__ __forceinline__ unsigned short f2us(float f){ union{bf16 b; unsigned short u;} v; v.b = __float2bfloat16(f); return v.u; }

// fast transcendentals: v_exp_f32 + v_rcp_f32 (~1 ulp each; bf16 outputs don't care)
__device__ __forceinline__ float fast_sig(float x){
  float e = __builtin_amdgcn_exp2f(-1.4426950408889634f * x);
  return __builtin_amdgcn_rcpf(1.f + e);
}
__device__ __forceinline__ float fast_tanh(float x){
  float ax = fabsf(x);
  float e = __builtin_amdgcn_exp2f(-2.885390081777927f * ax);
  float r = (1.f - e) * __builtin_amdgcn_rcpf(1.f + e);
  return copysignf(r, x);
}

// async 16B global -> LDS (dest = wave-uniform base + lane*16)
__device__ __forceinline__ void gload_lds16(const bf16* g, bf16* l){
  __builtin_amdgcn_global_load_lds(
    (const __attribute__((address_space(1))) unsigned int*)g,
    (__attribute__((address_space(3))) unsigned int*)l, 16, 0, 0);
}

// ---------------- staging kernels ----------------

__global__ void cvt_b16(bf16* __restrict__ dst, const float* __restrict__ src, int n8){
  int e = blockIdx.x*256 + threadIdx.x;
  if (e >= n8) return;
  const float4* s = (const float4*)(src + (size_t)e*8);
  float4 a = s[0], b = s[1];
  us8v o = { f2us(a.x), f2us(a.y), f2us(a.z), f2us(a.w),
             f2us(b.x), f2us(b.y), f2us(b.z), f2us(b.w) };
  *(us8v*)(dst + (size_t)e*8) = o;
}

struct PackArgs { const float* s[16]; bf16* d[16]; int dk[16]; int ro[16]; int co[16]; };
__global__ void pack_all(PackArgs pa){
  int idx = blockIdx.x >> 7;               // 128 blocks per 512x512 matrix
  int e = (blockIdx.x & 127)*256 + threadIdx.x;   // 32768 8-elem chunks
  int r = e >> 6, c8 = e & 63;
  const float4* s = (const float4*)(pa.s[idx] + (size_t)r*512 + c8*8);
  float4 a = s[0], b = s[1];
  us8v o = { f2us(a.x), f2us(a.y), f2us(a.z), f2us(a.w),
             f2us(b.x), f2us(b.y), f2us(b.z), f2us(b.w) };
  *(us8v*)(pa.d[idx] + (size_t)(pa.ro[idx] + r)*pa.dk[idx] + pa.co[idx] + c8*8) = o;
}

// roots: hd[root]=h[root]; sA[2t]=sA[2t+1]=h[root]
__global__ void roots_k(bf16* __restrict__ hd, bf16* __restrict__ sA, const bf16* __restrict__ h){
  int e = blockIdx.x*256 + threadIdx.x;    // 512
  int t = e >> 6, c8 = e & 63;
  size_t off = ((size_t)t*NPT + 4094)*FD + c8*8;
  us8v v = *(const us8v*)(h + off);
  *(us8v*)(hd + off) = v;
  *(us8v*)(sA + (size_t)(2*t)*FD + c8*8) = v;
  *(us8v*)(sA + (size_t)(2*t+1)*FD + c8*8) = v;
}

// ---------------- scalar epilogue (gemm_small only) ----------------
__device__ __forceinline__ void epi4(
    const f4v& a, int rbase, int n, int M, int mode,
    const float* __restrict__ bias0, const float* __restrict__ bias1,
    const bf16* __restrict__ zb, const bf16* __restrict__ sb,
    const bf16* __restrict__ xw,
    bf16* __restrict__ o0, bf16* __restrict__ o1,
    bf16* __restrict__ hO, float* __restrict__ outF,
    int o_start, int o_log2, bf16* __restrict__ sN, int smode)
{
  if (rbase >= M) return;
  const int omask = (1 << o_log2) - 1;
  if (mode == 1){
    #pragma unroll
    for (int i = 0; i < 4; ++i){
      int row = rbase + i; if (row >= M) break;
      int tree = row >> o_log2, pos = row & omask;
      float v = a[i] + b2f(xw[((size_t)tree*NPT + o_start + pos)*1024 + n]);
      if (n < 512){
        o0[(size_t)row*FD + n] = f2b(fast_sig(v + bias0[n]));
      } else {
        float r = fast_sig(v + bias1[n-512]);
        size_t off = (size_t)row*FD + (n-512);
        o1[off] = f2b(r * b2f(sb[off]));
      }
    }
  } else { // mode 2
    float hv[4];
    #pragma unroll
    for (int i = 0; i < 4; ++i){
      int row = rbase + i;
      if (row >= M){ hv[i] = 0.f; continue; }
      float c = fast_tanh(a[i]);
      size_t off = (size_t)row*FD + n;
      float z = b2f(zb[off]);
      float s = b2f(sb[off]);
      float h = z*s + (1.f - z)*c;
      hv[i] = h;
      int tree = row >> o_log2, pos = row & omask;
      hO[((size_t)tree*NPT + o_start + pos)*FD + n] = f2b(h);
    }
    if (smode == 1){
      if (rbase + 1 < M) sN[(size_t)(rbase>>1)*FD + n] = f2b(hv[0] + hv[1]);
      if (rbase + 3 < M) sN[(size_t)((rbase>>1) + 1)*FD + n] = f2b(hv[2] + hv[3]);
    } else if (smode == 2){
      #pragma unroll
      for (int i = 0; i < 4; ++i){
        int row = rbase + i; if (row >= M) break;
        bf16 hb = f2b(hv[i]);
        sN[(size_t)(2*row)*FD + n] = hb;
        sN[(size_t)(2*row+1)*FD + n] = hb;
      }
    }
  }
}

// ---------------- big GEMM: 128x128 tile, BK=64, swizzled LDS ----------------
// modes: 1 gates; 2 cand; 3 precompute (N=1024 raw bf16); 4 out (f32 + biases);
//        5 fused leaf (h=(1-sig(xw))*tanh(v); pair-sum -> sN)
#define CPAD 132
__global__ __launch_bounds__(256) void gemm_big(
    const bf16* __restrict__ A0, const bf16* __restrict__ A1,
    const bf16* __restrict__ Wp, int M, int K, int ldb,
    int a_start, int a_log2, int o_start, int o_log2,
    const float* __restrict__ bias0, const float* __restrict__ bias1,
    const bf16* __restrict__ zb, const bf16* __restrict__ sb,
    const bf16* __restrict__ xw,
    bf16* __restrict__ o0, bf16* __restrict__ o1,
    bf16* __restrict__ hO, float* __restrict__ outF,
    bf16* __restrict__ sN, int smode, int mode)
{
  __shared__ __align__(16) char smemraw[64*CPAD*4];   // 33.8KB: staging (32KB) U half-C f32
  bf16* As = (bf16*)smemraw;
  bf16* Bs = As + 128*64;
  float* Cf = (float*)smemraw;

  const int t = threadIdx.x, lane = t & 63, wid = t >> 6;
  const int wr = wid >> 1, wc = wid & 1;
  const int lr = lane & 15, quad = lane >> 4;

  // XCD-aware bijective swizzle; n_blk fastest within a chunk so the 8 blocks
  // sharing an A-panel are temporally adjacent on ONE XCD (A-panel L2-resident).
  const int gx = gridDim.x, gy = gridDim.y;
  int nwg = gx * gy;
  int id = blockIdx.y * gx + blockIdx.x;
  int q = nwg >> 3, r8 = nwg & 7;
  int xcd = id & 7, jj = id >> 3;
  int wg = (xcd < r8 ? xcd*(q+1) : r8*(q+1) + (xcd - r8)*q) + jj;
  const int m_blk = (wg / gy) * 128, n_blk = (wg % gy) * 128;

  const int Mm1 = M - 1;
  const int amask = (1 << a_log2) - 1;
  const int wbase = (t & ~63);

  // hoisted per-thread staging sources (chunk g stored at slot g^(row&7))
  const bf16* a0p[4]; const bf16* a1p[4]; const bf16* bp[4];
  #pragma unroll
  for (int p = 0; p < 4; ++p){
    int c = p*256 + t;
    int rl = c >> 3, slot = c & 7;
    int g = slot ^ (rl & 7);
    int r = m_blk + rl; if (r > Mm1) r = Mm1;
    int tr = r >> a_log2, po = r & amask;
    a0p[p] = A0 + ((size_t)tr*NPT + a_start + po)*FD + g*8;
    a1p[p] = A1 + (size_t)r*FD + g*8;
    bp[p]  = Wp + (size_t)(n_blk + rl)*ldb + g*8;
  }

  f4v acc[4][4] = {};

  for (int k0 = 0; k0 < K; k0 += 64){
    #pragma unroll
    for (int p = 0; p < 4; ++p){
      const bf16* src = (k0 < 512) ? (a0p[p] + k0) : (a1p[p] + (k0 - 512));
      gload_lds16(src, &As[(size_t)(p*256 + wbase)*8]);
    }
    #pragma unroll
    for (int p = 0; p < 4; ++p)
      gload_lds16(bp[p] + k0, &Bs[(size_t)(p*256 + wbase)*8]);
    __syncthreads();

    #pragma unroll
    for (int kh = 0; kh < 2; ++kh){
      int cidx = kh*4 + quad;
      bf8v af[4], bv[4];
      #pragma unroll
      for (int i = 0; i < 4; ++i){
        int ra = wr*64 + i*16 + lr;
        af[i] = *(const bf8v*)&As[ra*64 + ((cidx ^ (ra & 7))*8)];
        int rb = wc*64 + i*16 + lr;
        bv[i] = *(const bf8v*)&Bs[rb*64 + ((cidx ^ (rb & 7))*8)];
      }
      #pragma unroll
      for (int i = 0; i < 4; ++i)
        #pragma unroll
        for (int j = 0; j < 4; ++j)
          acc[i][j] = __builtin_amdgcn_mfma_f32_16x16x32_bf16(af[i], bv[j], acc[i][j], 0, 0, 0);
    }
    __syncthreads();
  }

  const int omask = (1 << o_log2) - 1;
  const int L0 = (t >> 4) * 4;          // local row base in the 64-row half-tile
  const int c0l = (t & 15) * 8;
  const int n0 = n_blk + c0l;
  const int grb0 = m_blk + (L0 >> 5)*64 + (L0 & 31);   // + p*32 per pass

  #define LOADV(i, vv) { float4 _v0 = *(const float4*)&Cf[(L0+(i))*CPAD + c0l]; \
                         float4 _v1 = *(const float4*)&Cf[(L0+(i))*CPAD + c0l + 4]; \
                         vv[0]=_v0.x; vv[1]=_v0.y; vv[2]=_v0.z; vv[3]=_v0.w; \
                         vv[4]=_v1.x; vv[5]=_v1.y; vv[6]=_v1.z; vv[7]=_v1.w; }

  #pragma unroll
  for (int p = 0; p < 2; ++p){
    __syncthreads();   // protect staging (p=0) / previous pass reads (p=1)
    #pragma unroll
    for (int mt2 = 0; mt2 < 2; ++mt2){
      int lrow = wr*32 + mt2*16 + quad*4;
      #pragma unroll
      for (int nt = 0; nt < 4; ++nt){
        int c = wc*64 + nt*16 + lr;
        #pragma unroll
        for (int i = 0; i < 4; ++i)
          Cf[(lrow+i)*CPAD + c] = acc[2*p+mt2][nt][i];
      }
    }
    __syncthreads();

    const int gr = grb0 + p*32;

    if (mode == 3){
      #pragma unroll
      for (int i = 0; i < 4; ++i){
        int row = gr + i; if (row >= M) continue;
        float vv[8]; LOADV(i, vv);
        us8v o;
        #pragma unroll
        for (int k2 = 0; k2 < 8; ++k2) o[k2] = f2us(vv[k2]);
        *(us8v*)(o0 + (size_t)row*1024 + n0) = o;
      }
    } else if (mode == 4){
      float bb[8];
      *(float4*)&bb[0] = *(const float4*)&bias0[n0];
      *(float4*)&bb[4] = *(const float4*)&bias0[n0+4];
      float b2v[8];
      *(float4*)&b2v[0] = *(const float4*)&bias1[n0];
      *(float4*)&b2v[4] = *(const float4*)&bias1[n0+4];
      #pragma unroll
      for (int k2 = 0; k2 < 8; ++k2) bb[k2] += b2v[k2];
      #pragma unroll
      for (int i = 0; i < 4; ++i){
        int row = gr + i; if (row >= M) continue;
        float vv[8]; LOADV(i, vv);
        float4 o0v = { vv[0]+bb[0], vv[1]+bb[1], vv[2]+bb[2], vv[3]+bb[3] };
        float4 o1v = { vv[4]+bb[4], vv[5]+bb[5], vv[6]+bb[6], vv[7]+bb[7] };
        *(float4*)(outF + (size_t)row*FD + n0)     = o0v;
        *(float4*)(outF + (size_t)row*FD + n0 + 4) = o1v;
      }
    } else if (mode == 1){
      if (n0 < 512){
        float bb[8];
        *(float4*)&bb[0] = *(const float4*)&bias0[n0];
        *(float4*)&bb[4] = *(const float4*)&bias0[n0+4];
        #pragma unroll
        for (int i = 0; i < 4; ++i){
          int row = gr + i; if (row >= M) continue;
          size_t node = (size_t)(row >> o_log2)*NPT + o_start + (row & omask);
          us8v xv = *(const us8v*)(xw + node*1024 + n0);
          float vv[8]; LOADV(i, vv);
          us8v o;
          #pragma unroll
          for (int k2 = 0; k2 < 8; ++k2)
            o[k2] = f2us(fast_sig(vv[k2] + us2f(xv[k2]) + bb[k2]));
          *(us8v*)(o0 + (size_t)row*FD + n0) = o;
        }
      } else {
        int n5 = n0 - 512;
        float bb[8];
        *(float4*)&bb[0] = *(const float4*)&bias1[n5];
        *(float4*)&bb[4] = *(const float4*)&bias1[n5+4];
        #pragma unroll
        for (int i = 0; i < 4; ++i){
          int row = gr + i; if (row >= M) continue;
          size_t node = (size_t)(row >> o_log2)*NPT + o_start + (row & omask);
          us8v xv = *(const us8v*)(xw + node*1024 + n0);
          us8v sv = *(const us8v*)(sb + (size_t)row*FD + n5);
          float vv[8]; LOADV(i, vv);
          us8v o;
          #pragma unroll
          for (int k2 = 0; k2 < 8; ++k2){
            float r = fast_sig(vv[k2] + us2f(xv[k2]) + bb[k2]);
            o[k2] = f2us(r * us2f(sv[k2]));
          }
          *(us8v*)(o1 + (size_t)row*FD + n5) = o;
        }
      }
    } else if (mode == 5){   // fused leaf
      float hprev[8];
      #pragma unroll
      for (int i = 0; i < 4; ++i){
        int row = gr + i; if (row >= M) continue;
        size_t node = (size_t)(row >> o_log2)*NPT + o_start + (row & omask);
        us8v zv = *(const us8v*)(xw + node*1024 + n0);
        float vv[8]; LOADV(i, vv);
        float hc[8]; us8v hb;
        #pragma unroll
        for (int k2 = 0; k2 < 8; ++k2){
          float h = (1.f - fast_sig(us2f(zv[k2]))) * fast_tanh(vv[k2]);
          hc[k2] = h; hb[k2] = f2us(h);
        }
        *(us8v*)(hO + node*FD + n0) = hb;
        if (i & 1){
          us8v ss;
          #pragma unroll
          for (int k2 = 0; k2 < 8; ++k2) ss[k2] = f2us(hprev[k2] + hc[k2]);
          *(us8v*)(sN + (size_t)(row>>1)*FD + n0) = ss;
        } else {
          #pragma unroll
          for (int k2 = 0; k2 < 8; ++k2) hprev[k2] = hc[k2];
        }
      }
    } else {   // mode 2: cand
      float hprev[8];
      #pragma unroll
      for (int i = 0; i < 4; ++i){
        int row = gr + i; if (row >= M) continue;
        us8v zv = *(const us8v*)(zb + (size_t)row*FD + n0);
        us8v sv = *(const us8v*)(sb + (size_t)row*FD + n0);
        float vv[8]; LOADV(i, vv);
        float hc[8]; us8v hb;
        #pragma unroll
        for (int k2 = 0; k2 < 8; ++k2){
          float c = fast_tanh(vv[k2]);
          float z = us2f(zv[k2]);
          float s = us2f(sv[k2]);
          float h = z*s + (1.f - z)*c;
          hc[k2] = h; hb[k2] = f2us(h);
        }
        size_t node = (size_t)(row >> o_log2)*NPT + o_start + (row & omask);
        *(us8v*)(hO + node*FD + n0) = hb;
        if (smode == 1){
          if (i & 1){
            us8v ss;
            #pragma unroll
            for (int k2 = 0; k2 < 8; ++k2) ss[k2] = f2us(hprev[k2] + hc[k2]);
            *(us8v*)(sN + (size_t)(row>>1)*FD + n0) = ss;
          } else {
            #pragma unroll
            for (int k2 = 0; k2 < 8; ++k2) hprev[k2] = hc[k2];
          }
        } else if (smode == 2){
          *(us8v*)(sN + (size_t)(2*row)*FD + n0) = hb;
          *(us8v*)(sN + (size_t)(2*row+1)*FD + n0) = hb;
        }
      }
    }
  }
  #undef LOADV
}

// ---------------- small GEMM: 64x64 tile, direct loads, no barriers ----------------
// K-loop split into A0-region / A1-region (no per-iteration select) and unrolled
// so the compiler pipelines L2-hit loads ahead of MFMAs (latency-bound regime).
__global__ __launch_bounds__(256) void gemm_small(
    const bf16* __restrict__ A0, const bf16* __restrict__ A1,
    const bf16* __restrict__ Wp, int M, int K, int ldb,
    int a_start, int a_log2, int o_start, int o_log2,
    const float* __restrict__ bias0, const float* __restrict__ bias1,
    const bf16* __restrict__ zb, const bf16* __restrict__ sb,
    const bf16* __restrict__ xw,
    bf16* __restrict__ o0, bf16* __restrict__ o1,
    bf16* __restrict__ hO, float* __restrict__ outF,
    bf16* __restrict__ sN, int smode, int mode)
{
  const int lane = threadIdx.x & 63, wid = threadIdx.x >> 6;
  const int wr = wid >> 1, wc = wid & 1;
  const int m_base = blockIdx.x*64 + wr*32;
  const int n_base = blockIdx.y*64 + wc*32;
  const int lr = lane & 15, quad = lane >> 4;
  const int Mm1 = M - 1;
  const int amask = (1 << a_log2) - 1;

  f4v acc[2][2] = {};

  const bf16 *a0p[2], *a1p[2], *bp[2];
  #pragma unroll
  for (int mt = 0; mt < 2; ++mt){
    int m = m_base + mt*16 + lr; if (m > Mm1) m = Mm1;
    int tr = m >> a_log2, po = m & amask;
    a0p[mt] = A0 + ((size_t)tr*NPT + a_start + po)*FD + quad*8;
    a1p[mt] = A1 + (size_t)m*FD + quad*8;
  }
  #pragma unroll
  for (int nt = 0; nt < 2; ++nt)
    bp[nt] = Wp + (size_t)(n_base + nt*16 + lr)*ldb + quad*8;

  // region 1: k in [0, min(K,512)) from A0
  const int K1 = K < 512 ? K : 512;
  #pragma unroll 8
  for (int k0 = 0; k0 < K1; k0 += 32){
    bf8v a[2], b[2];
    a[0] = *(const bf8v*)(a0p[0] + k0);
    a[1] = *(const bf8v*)(a0p[1] + k0);
    b[0] = *(const bf8v*)(bp[0] + k0);
    b[1] = *(const bf8v*)(bp[1] + k0);
    #pragma unroll
    for (int mt = 0; mt < 2; ++mt)
      #pragma unroll
      for (int nt = 0; nt < 2; ++nt)
        acc[mt][nt] = __builtin_amdgcn_mfma_f32_16x16x32_bf16(a[mt], b[nt], acc[mt][nt], 0, 0, 0);
  }
  // region 2: k in [512, K) from A1
  #pragma unroll 8
  for (int k0 = 512; k0 < K; k0 += 32){
    bf8v a[2], b[2];
    a[0] = *(const bf8v*)(a1p[0] + (k0 - 512));
    a[1] = *(const bf8v*)(a1p[1] + (k0 - 512));
    b[0] = *(const bf8v*)(bp[0] + k0);
    b[1] = *(const bf8v*)(bp[1] + k0);
    #pragma unroll
    for (int mt = 0; mt < 2; ++mt)
      #pragma unroll
      for (int nt = 0; nt < 2; ++nt)
        acc[mt][nt] = __builtin_amdgcn_mfma_f32_16x16x32_bf16(a[mt], b[nt], acc[mt][nt], 0, 0, 0);
  }

  #pragma unroll
  for (int mt = 0; mt < 2; ++mt){
    int rbase = m_base + mt*16 + quad*4;
    #pragma unroll
    for (int nt = 0; nt < 2; ++nt){
      int n = n_base + nt*16 + lr;
      epi4(acc[mt][nt], rbase, n, M, mode, bias0, bias1, zb, sb, xw, o0, o1, hO, outF,
           o_start, o_log2, sN, smode);
    }
  }
}

// ---------------- host launcher ----------------

extern "C" void kernel_launch(void* const* d_in, const int* in_sizes, int n_in,
                              void* d_out, int out_size, void* d_ws, size_t ws_size,
                              hipStream_t stream)
{
  const float* feat = (const float*)d_in[0];
  const float* Wh   = (const float*)d_in[1];
  const float* Wz   = (const float*)d_in[2];
  const float* Wr   = (const float*)d_in[3];
  const float* Uh   = (const float*)d_in[4];
  const float* Uz   = (const float*)d_in[5];
  const float* bUz  = (const float*)d_in[6];
  const float* Ur   = (const float*)d_in[7];
  const float* bUr  = (const float*)d_in[8];
  const float* Whd  = (const float*)d_in[9];
  const float* Wzd  = (const float*)d_in[10];
  const float* Wrd  = (const float*)d_in[11];
  const float* Uhd  = (const float*)d_in[12];
  const float* Uzd  = (const float*)d_in[13];
  const float* bUzd = (const float*)d_in[14];
  const float* Urd  = (const float*)d_in[15];
  const float* bUrd = (const float*)d_in[16];
  const float* W1   = (const float*)d_in[17];
  const float* b1   = (const float*)d_in[18];
  const float* W2   = (const float*)d_in[19];
  const float* b2   = (const float*)d_in[20];
  float* out = (float*)d_out;

  int starts[12], szs[12];
  { int s = 0, sz = 2048; for (int l = 0; l < 12; ++l){ starts[l] = s; szs[l] = sz; s += sz; sz >>= 1; } }

  char* p = (char*)d_ws;
  auto take = [&](size_t b)->char*{ char* q = p; p += (b + 255) & ~(size_t)255; return q; };
  bf16* featb = (bf16*)take((size_t)NT*FD*2);
  bf16* h_b   = (bf16*)take((size_t)NT*FD*2);
  bf16* hd_b  = (bf16*)take((size_t)NT*FD*2);
  bf16* Wzr_u = (bf16*)take((size_t)1024*512*2);
  bf16* Wzr_d = (bf16*)take((size_t)1024*512*2);
  bf16* Uzr_u = (bf16*)take((size_t)1024*512*2);
  bf16* Uzr_d = (bf16*)take((size_t)1024*512*2);
  bf16* Whu   = (bf16*)take((size_t)512*1024*2);
  bf16* Whu_d = (bf16*)take((size_t)512*1024*2);
  bf16* Wout  = (bf16*)take((size_t)512*1024*2);
  bf16* z16   = (bf16*)take((size_t)16384*512*2);
  bf16* rh16  = (bf16*)take((size_t)16384*512*2);
  bf16* sP0   = (bf16*)take((size_t)16384*512*2);
  bf16* sP1   = (bf16*)take((size_t)16384*512*2);
  if ((size_t)(p - (char*)d_ws) > ws_size) return;

  // xWzr = per-node x@[Wz|Wr] (NT x 1024 bf16) lives in d_out as scratch
  bf16* xWzr = (bf16*)d_out;

  // --- stage inputs: 2 launches ---
  cvt_b16<<<(NT*FD/8 + 255)/256, 256, 0, stream>>>(featb, feat, NT*FD/8);
  PackArgs pa;
  int pi = 0;
  auto pk = [&](const float* src, bf16* dst, int dk, int ro, int co){
    pa.s[pi] = src; pa.d[pi] = dst; pa.dk[pi] = dk; pa.ro[pi] = ro; pa.co[pi] = co; ++pi;
  };
  pk(Wz, Wzr_u, 512, 0, 0);    pk(Wr, Wzr_u, 512, 512, 0);
  pk(Wzd, Wzr_d, 512, 0, 0);   pk(Wrd, Wzr_d, 512, 512, 0);
  pk(Uz, Uzr_u, 512, 0, 0);    pk(Ur, Uzr_u, 512, 512, 0);
  pk(Uzd, Uzr_d, 512, 0, 0);   pk(Urd, Uzr_d, 512, 512, 0);
  pk(Wh, Whu, 1024, 0, 0);     pk(Uh, Whu, 1024, 0, 512);
  pk(Whd, Whu_d, 1024, 0, 0);  pk(Uhd, Whu_d, 1024, 0, 512);
  pk(W1, Wout, 1024, 0, 0);    pk(W2, Wout, 1024, 0, 512);
  pack_all<<<14*128, 256, 0, stream>>>(pa);

  auto gemm = [&](const bf16* A0, const bf16* A1, const bf16* Wp, int M, int N, int K, int ldb,
                  int a_start, int a_log2, int o_start, int o_log2,
                  const float* bias0, const float* bias1,
                  const bf16* zb, const bf16* sb, const bf16* xw,
                  bf16* o0, bf16* o1, bf16* hO, float* outF,
                  bf16* sN, int smode, int mode){
    if (M >= 16384){
      dim3 g((M + 127)/128, N/128);
      gemm_big<<<g, 256, 0, stream>>>(A0, A1, Wp, M, K, ldb, a_start, a_log2, o_start, o_log2,
                                      bias0, bias1, zb, sb, xw, o0, o1, hO, outF, sN, smode, mode);
    } else {
      dim3 g((M + 63)/64, N/64);
      gemm_small<<<g, 256, 0, stream>>>(A0, A1, Wp, M, K, ldb, a_start, a_log2, o_start, o_log2,
                                        bias0, bias1, zb, sb, xw, o0, o1, hO, outF, sN, smode, mode);
    }
  };

  // --- precompute-up: xWzr[node] = x@[Wz|Wr] for ALL nodes ---
  gemm(featb, featb, Wzr_u, NT, 1024, 512, 512, 0, 26, 0, 26,
       nullptr, nullptr, nullptr, nullptr, nullptr, xWzr, nullptr, nullptr, nullptr, nullptr, 0, 3);

  // --- leaves fused: h = (1-sig(xWzr_z))*tanh(x@Wh); pair-sum -> sP0 (mode 5) ---
  gemm(featb, featb, Whu, 16384, 512, 512, 1024, 0, 11, 0, 11,
       nullptr, nullptr, nullptr, nullptr, xWzr, nullptr, nullptr, h_b, nullptr, sP0, 1, 5);

  // --- bottom-up ---
  for (int l = 0; l < 11; ++l){
    int Mf = 8*szs[l+1];
    int al2 = 10 - l, os = starts[l+1];
    bf16* sCur = (l & 1) ? sP1 : sP0;
    bf16* sNext = (l & 1) ? sP0 : sP1;
    int smode = (l < 10) ? 1 : 0;
    gemm(sCur, sCur, Uzr_u, Mf, 1024, 512, 512, 0, 26, os, al2,
         bUz, bUr, nullptr, sCur, xWzr, z16, rh16, nullptr, nullptr, nullptr, 0, 1);
    gemm(featb, rh16, Whu, Mf, 512, 1024, 1024, os, al2, os, al2,
         nullptr, nullptr, z16, sCur, nullptr, nullptr, nullptr, h_b, nullptr, sNext, smode, 2);
  }

  // --- precompute-down: xWzr[node] = x@[Wzd|Wrd] ---
  gemm(featb, featb, Wzr_d, NT, 1024, 512, 512, 0, 26, 0, 26,
       nullptr, nullptr, nullptr, nullptr, nullptr, xWzr, nullptr, nullptr, nullptr, nullptr, 0, 3);

  // --- roots ---
  roots_k<<<2, 256, 0, stream>>>(hd_b, sP0, h_b);

  // --- top-down ---
  for (int l = 10; l >= 0; --l){
    int Ms = 8*szs[l];
    int al2 = 11 - l, os = starts[l];
    bf16* sCur = ((10 - l) & 1) ? sP1 : sP0;
    bf16* sNext = ((10 - l) & 1) ? sP0 : sP1;
    int smode = (l > 0) ? 2 : 0;
    gemm(sCur, sCur, Uzr_d, Ms, 1024, 512, 512, 0, 26, os, al2,
         bUzd, bUrd, nullptr, sCur, xWzr, z16, rh16, nullptr, nullptr, nullptr, 0, 1);
    gemm(featb, rh16, Whu_d, Ms, 512, 1024, 1024, os, al2, os, al2,
         nullptr, nullptr, z16, sCur, nullptr, nullptr, nullptr, hd_b, nullptr, sNext, smode, 2);
  }

  // --- output: [h|hd] @ [W1|W2].T + b1 + b2 ---
  gemm(h_b, hd_b, Wout, NT, 512, 1024, 1024, 0, 26, 0, 26,
       b1, b2, nullptr, nullptr, nullptr, nullptr, nullptr, nullptr, out, nullptr, 0, 4);
}

// Round 11
// 1142.188 us; speedup vs baseline: 1.5724x; 1.2555x over previous
//
#include <hip/hip_runtime.h>
#include <hip/hip_bf16.h>
#include <cmath>
#include <cstdint>

#define NPT 4095      // nodes per tree
#define NT  32760     // total nodes (8 trees)
#define FD  512       // hidden/feature dim

using bf16 = __hip_bfloat16;
using bf8v = __attribute__((ext_vector_type(8))) short;   // 8 bf16 (4 VGPRs)
using us8v = __attribute__((ext_vector_type(8))) unsigned short;
using f4v  = __attribute__((ext_vector_type(4))) float;   // MFMA accumulator

__device__ __forceinline__ float b2f(bf16 x){ return __bfloat162float(x); }
__device__ __forceinline__ bf16  f2b(float x){ return __float2bfloat16(x); }
__device__ __forceinline__ float us2f(unsigned short u){ union{unsigned int i; float f;} v; v.i = ((unsigned)u)<<16; return v.f; }
__device__ __forceinline__ unsigned short f2us(float f){ union{bf16 b; unsigned short u;} v; v.b = __float2bfloat16(f); return v.u; }

// fast transcendentals: v_exp_f32 + v_rcp_f32 (~1 ulp each; bf16 outputs don't care)
__device__ __forceinline__ float fast_sig(float x){
  float e = __builtin_amdgcn_exp2f(-1.4426950408889634f * x);
  return __builtin_amdgcn_rcpf(1.f + e);
}
__device__ __forceinline__ float fast_tanh(float x){
  float ax = fabsf(x);
  float e = __builtin_amdgcn_exp2f(-2.885390081777927f * ax);
  float r = (1.f - e) * __builtin_amdgcn_rcpf(1.f + e);
  return copysignf(r, x);
}

// async 16B global -> LDS (dest = wave-uniform base + lane*16)
__device__ __forceinline__ void gload_lds16(const bf16* g, bf16* l){
  __builtin_amdgcn_global_load_lds(
    (const __attribute__((address_space(1))) unsigned int*)g,
    (__attribute__((address_space(3))) unsigned int*)l, 16, 0, 0);
}

// ---------------- staging kernels ----------------

__global__ void cvt_b16(bf16* __restrict__ dst, const float* __restrict__ src, int n8){
  int e = blockIdx.x*256 + threadIdx.x;
  if (e >= n8) return;
  const float4* s = (const float4*)(src + (size_t)e*8);
  float4 a = s[0], b = s[1];
  us8v o = { f2us(a.x), f2us(a.y), f2us(a.z), f2us(a.w),
             f2us(b.x), f2us(b.y), f2us(b.z), f2us(b.w) };
  *(us8v*)(dst + (size_t)e*8) = o;
}

struct PackArgs { const float* s[16]; bf16* d[16]; int dk[16]; int ro[16]; int co[16]; };
__global__ void pack_all(PackArgs pa){
  int idx = blockIdx.x >> 7;               // 128 blocks per 512x512 matrix
  int e = (blockIdx.x & 127)*256 + threadIdx.x;   // 32768 8-elem chunks
  int r = e >> 6, c8 = e & 63;
  const float4* s = (const float4*)(pa.s[idx] + (size_t)r*512 + c8*8);
  float4 a = s[0], b = s[1];
  us8v o = { f2us(a.x), f2us(a.y), f2us(a.z), f2us(a.w),
             f2us(b.x), f2us(b.y), f2us(b.z), f2us(b.w) };
  *(us8v*)(pa.d[idx] + (size_t)(pa.ro[idx] + r)*pa.dk[idx] + pa.co[idx] + c8*8) = o;
}

// roots: hd[root]=h[root]; sA[2t]=sA[2t+1]=h[root]
__global__ void roots_k(bf16* __restrict__ hd, bf16* __restrict__ sA, const bf16* __restrict__ h){
  int e = blockIdx.x*256 + threadIdx.x;    // 512
  int t = e >> 6, c8 = e & 63;
  size_t off = ((size_t)t*NPT + 4094)*FD + c8*8;
  us8v v = *(const us8v*)(h + off);
  *(us8v*)(hd + off) = v;
  *(us8v*)(sA + (size_t)(2*t)*FD + c8*8) = v;
  *(us8v*)(sA + (size_t)(2*t+1)*FD + c8*8) = v;
}

// ---------------- scalar epilogue (gemm_small only) ----------------
__device__ __forceinline__ void epi4(
    const f4v& a, int rbase, int n, int M, int mode,
    const float* __restrict__ bias0, const float* __restrict__ bias1,
    const bf16* __restrict__ zb, const bf16* __restrict__ sb,
    const bf16* __restrict__ xw,
    bf16* __restrict__ o0, bf16* __restrict__ o1,
    bf16* __restrict__ hO, float* __restrict__ outF,
    int o_start, int o_log2, bf16* __restrict__ sN, int smode)
{
  if (rbase >= M) return;
  const int omask = (1 << o_log2) - 1;
  if (mode == 1){
    #pragma unroll
    for (int i = 0; i < 4; ++i){
      int row = rbase + i; if (row >= M) break;
      int tree = row >> o_log2, pos = row & omask;
      float v = a[i] + b2f(xw[((size_t)tree*NPT + o_start + pos)*1024 + n]);
      if (n < 512){
        o0[(size_t)row*FD + n] = f2b(fast_sig(v + bias0[n]));
      } else {
        float r = fast_sig(v + bias1[n-512]);
        size_t off = (size_t)row*FD + (n-512);
        o1[off] = f2b(r * b2f(sb[off]));
      }
    }
  } else { // mode 2
    float hv[4];
    #pragma unroll
    for (int i = 0; i < 4; ++i){
      int row = rbase + i;
      if (row >= M){ hv[i] = 0.f; continue; }
      float c = fast_tanh(a[i]);
      size_t off = (size_t)row*FD + n;
      float z = b2f(zb[off]);
      float s = b2f(sb[off]);
      float h = z*s + (1.f - z)*c;
      hv[i] = h;
      int tree = row >> o_log2, pos = row & omask;
      hO[((size_t)tree*NPT + o_start + pos)*FD + n] = f2b(h);
    }
    if (smode == 1){
      if (rbase + 1 < M) sN[(size_t)(rbase>>1)*FD + n] = f2b(hv[0] + hv[1]);
      if (rbase + 3 < M) sN[(size_t)((rbase>>1) + 1)*FD + n] = f2b(hv[2] + hv[3]);
    } else if (smode == 2){
      #pragma unroll
      for (int i = 0; i < 4; ++i){
        int row = rbase + i; if (row >= M) break;
        bf16 hb = f2b(hv[i]);
        sN[(size_t)(2*row)*FD + n] = hb;
        sN[(size_t)(2*row+1)*FD + n] = hb;
      }
    }
  }
}

// ---------------- vector epilogue body (big/mid), 4 rows x 8 cols per call ----------------
// vv: LOADV'd accumulator rows from LDS; gr/n0 = global row base / col base.
__device__ __forceinline__ void epi_vec4(
    int gr, int n0, int M, int mode,
    const float* __restrict__ bias0, const float* __restrict__ bias1,
    const bf16* __restrict__ zb, const bf16* __restrict__ sb,
    const bf16* __restrict__ xw,
    bf16* __restrict__ o0, bf16* __restrict__ o1,
    bf16* __restrict__ hO, float* __restrict__ outF,
    int o_start, int o_log2, bf16* __restrict__ sN, int smode,
    const float* __restrict__ Cf, int L0, int c0l, int cpad)
{
  const int omask = (1 << o_log2) - 1;

  #define LOADV(i, vv) { float4 _v0 = *(const float4*)&Cf[(L0+(i))*cpad + c0l]; \
                         float4 _v1 = *(const float4*)&Cf[(L0+(i))*cpad + c0l + 4]; \
                         vv[0]=_v0.x; vv[1]=_v0.y; vv[2]=_v0.z; vv[3]=_v0.w; \
                         vv[4]=_v1.x; vv[5]=_v1.y; vv[6]=_v1.z; vv[7]=_v1.w; }

  if (mode == 3){
    #pragma unroll
    for (int i = 0; i < 4; ++i){
      int row = gr + i; if (row >= M) continue;
      float vv[8]; LOADV(i, vv);
      us8v o;
      #pragma unroll
      for (int k2 = 0; k2 < 8; ++k2) o[k2] = f2us(vv[k2]);
      *(us8v*)(o0 + (size_t)row*1024 + n0) = o;
    }
  } else if (mode == 4){
    float bb[8];
    *(float4*)&bb[0] = *(const float4*)&bias0[n0];
    *(float4*)&bb[4] = *(const float4*)&bias0[n0+4];
    float b2v[8];
    *(float4*)&b2v[0] = *(const float4*)&bias1[n0];
    *(float4*)&b2v[4] = *(const float4*)&bias1[n0+4];
    #pragma unroll
    for (int k2 = 0; k2 < 8; ++k2) bb[k2] += b2v[k2];
    #pragma unroll
    for (int i = 0; i < 4; ++i){
      int row = gr + i; if (row >= M) continue;
      float vv[8]; LOADV(i, vv);
      float4 o0v = { vv[0]+bb[0], vv[1]+bb[1], vv[2]+bb[2], vv[3]+bb[3] };
      float4 o1v = { vv[4]+bb[4], vv[5]+bb[5], vv[6]+bb[6], vv[7]+bb[7] };
      *(float4*)(outF + (size_t)row*FD + n0)     = o0v;
      *(float4*)(outF + (size_t)row*FD + n0 + 4) = o1v;
    }
  } else if (mode == 1){
    if (n0 < 512){
      float bb[8];
      *(float4*)&bb[0] = *(const float4*)&bias0[n0];
      *(float4*)&bb[4] = *(const float4*)&bias0[n0+4];
      #pragma unroll
      for (int i = 0; i < 4; ++i){
        int row = gr + i; if (row >= M) continue;
        size_t node = (size_t)(row >> o_log2)*NPT + o_start + (row & omask);
        us8v xv = *(const us8v*)(xw + node*1024 + n0);
        float vv[8]; LOADV(i, vv);
        us8v o;
        #pragma unroll
        for (int k2 = 0; k2 < 8; ++k2)
          o[k2] = f2us(fast_sig(vv[k2] + us2f(xv[k2]) + bb[k2]));
        *(us8v*)(o0 + (size_t)row*FD + n0) = o;
      }
    } else {
      int n5 = n0 - 512;
      float bb[8];
      *(float4*)&bb[0] = *(const float4*)&bias1[n5];
      *(float4*)&bb[4] = *(const float4*)&bias1[n5+4];
      #pragma unroll
      for (int i = 0; i < 4; ++i){
        int row = gr + i; if (row >= M) continue;
        size_t node = (size_t)(row >> o_log2)*NPT + o_start + (row & omask);
        us8v xv = *(const us8v*)(xw + node*1024 + n0);
        us8v sv = *(const us8v*)(sb + (size_t)row*FD + n5);
        float vv[8]; LOADV(i, vv);
        us8v o;
        #pragma unroll
        for (int k2 = 0; k2 < 8; ++k2){
          float r = fast_sig(vv[k2] + us2f(xv[k2]) + bb[k2]);
          o[k2] = f2us(r * us2f(sv[k2]));
        }
        *(us8v*)(o1 + (size_t)row*FD + n5) = o;
      }
    }
  } else if (mode == 5){   // fused leaf
    float hprev[8];
    #pragma unroll
    for (int i = 0; i < 4; ++i){
      int row = gr + i; if (row >= M) continue;
      size_t node = (size_t)(row >> o_log2)*NPT + o_start + (row & omask);
      us8v zv = *(const us8v*)(xw + node*1024 + n0);
      float vv[8]; LOADV(i, vv);
      float hc[8]; us8v hb;
      #pragma unroll
      for (int k2 = 0; k2 < 8; ++k2){
        float h = (1.f - fast_sig(us2f(zv[k2]))) * fast_tanh(vv[k2]);
        hc[k2] = h; hb[k2] = f2us(h);
      }
      *(us8v*)(hO + node*FD + n0) = hb;
      if (i & 1){
        us8v ss;
        #pragma unroll
        for (int k2 = 0; k2 < 8; ++k2) ss[k2] = f2us(hprev[k2] + hc[k2]);
        *(us8v*)(sN + (size_t)(row>>1)*FD + n0) = ss;
      } else {
        #pragma unroll
        for (int k2 = 0; k2 < 8; ++k2) hprev[k2] = hc[k2];
      }
    }
  } else {   // mode 2: cand
    float hprev[8];
    #pragma unroll
    for (int i = 0; i < 4; ++i){
      int row = gr + i; if (row >= M) continue;
      us8v zv = *(const us8v*)(zb + (size_t)row*FD + n0);
      us8v sv = *(const us8v*)(sb + (size_t)row*FD + n0);
      float vv[8]; LOADV(i, vv);
      float hc[8]; us8v hb;
      #pragma unroll
      for (int k2 = 0; k2 < 8; ++k2){
        float c = fast_tanh(vv[k2]);
        float z = us2f(zv[k2]);
        float s = us2f(sv[k2]);
        float h = z*s + (1.f - z)*c;
        hc[k2] = h; hb[k2] = f2us(h);
      }
      size_t node = (size_t)(row >> o_log2)*NPT + o_start + (row & omask);
      *(us8v*)(hO + node*FD + n0) = hb;
      if (smode == 1){
        if (i & 1){
          us8v ss;
          #pragma unroll
          for (int k2 = 0; k2 < 8; ++k2) ss[k2] = f2us(hprev[k2] + hc[k2]);
          *(us8v*)(sN + (size_t)(row>>1)*FD + n0) = ss;
        } else {
          #pragma unroll
          for (int k2 = 0; k2 < 8; ++k2) hprev[k2] = hc[k2];
        }
      } else if (smode == 2){
        *(us8v*)(sN + (size_t)(2*row)*FD + n0) = hb;
        *(us8v*)(sN + (size_t)(2*row+1)*FD + n0) = hb;
      }
    }
  }
  #undef LOADV
}

// ---------------- big GEMM: 128x128 tile, BK=64, swizzled LDS ----------------
#define CPAD 132
__global__ __launch_bounds__(256) void gemm_big(
    const bf16* __restrict__ A0, const bf16* __restrict__ A1,
    const bf16* __restrict__ Wp, int M, int K, int ldb,
    int a_start, int a_log2, int o_start, int o_log2,
    const float* __restrict__ bias0, const float* __restrict__ bias1,
    const bf16* __restrict__ zb, const bf16* __restrict__ sb,
    const bf16* __restrict__ xw,
    bf16* __restrict__ o0, bf16* __restrict__ o1,
    bf16* __restrict__ hO, float* __restrict__ outF,
    bf16* __restrict__ sN, int smode, int mode)
{
  __shared__ __align__(16) char smemraw[64*CPAD*4];   // 33.8KB: staging (32KB) U half-C f32
  bf16* As = (bf16*)smemraw;
  bf16* Bs = As + 128*64;
  float* Cf = (float*)smemraw;

  const int t = threadIdx.x, lane = t & 63, wid = t >> 6;
  const int wr = wid >> 1, wc = wid & 1;
  const int lr = lane & 15, quad = lane >> 4;

  const int gx = gridDim.x, gy = gridDim.y;
  int nwg = gx * gy;
  int id = blockIdx.y * gx + blockIdx.x;
  int q = nwg >> 3, r8 = nwg & 7;
  int xcd = id & 7, jj = id >> 3;
  int wg = (xcd < r8 ? xcd*(q+1) : r8*(q+1) + (xcd - r8)*q) + jj;
  const int m_blk = (wg / gy) * 128, n_blk = (wg % gy) * 128;

  const int Mm1 = M - 1;
  const int amask = (1 << a_log2) - 1;
  const int wbase = (t & ~63);

  const bf16* a0p[4]; const bf16* a1p[4]; const bf16* bp[4];
  #pragma unroll
  for (int p = 0; p < 4; ++p){
    int c = p*256 + t;
    int rl = c >> 3, slot = c & 7;
    int g = slot ^ (rl & 7);
    int r = m_blk + rl; if (r > Mm1) r = Mm1;
    int tr = r >> a_log2, po = r & amask;
    a0p[p] = A0 + ((size_t)tr*NPT + a_start + po)*FD + g*8;
    a1p[p] = A1 + (size_t)r*FD + g*8;
    bp[p]  = Wp + (size_t)(n_blk + rl)*ldb + g*8;
  }

  f4v acc[4][4] = {};

  for (int k0 = 0; k0 < K; k0 += 64){
    #pragma unroll
    for (int p = 0; p < 4; ++p){
      const bf16* src = (k0 < 512) ? (a0p[p] + k0) : (a1p[p] + (k0 - 512));
      gload_lds16(src, &As[(size_t)(p*256 + wbase)*8]);
    }
    #pragma unroll
    for (int p = 0; p < 4; ++p)
      gload_lds16(bp[p] + k0, &Bs[(size_t)(p*256 + wbase)*8]);
    __syncthreads();

    #pragma unroll
    for (int kh = 0; kh < 2; ++kh){
      int cidx = kh*4 + quad;
      bf8v af[4], bv[4];
      #pragma unroll
      for (int i = 0; i < 4; ++i){
        int ra = wr*64 + i*16 + lr;
        af[i] = *(const bf8v*)&As[ra*64 + ((cidx ^ (ra & 7))*8)];
        int rb = wc*64 + i*16 + lr;
        bv[i] = *(const bf8v*)&Bs[rb*64 + ((cidx ^ (rb & 7))*8)];
      }
      #pragma unroll
      for (int i = 0; i < 4; ++i)
        #pragma unroll
        for (int j = 0; j < 4; ++j)
          acc[i][j] = __builtin_amdgcn_mfma_f32_16x16x32_bf16(af[i], bv[j], acc[i][j], 0, 0, 0);
    }
    __syncthreads();
  }

  const int L0 = (t >> 4) * 4;          // local row base in the 64-row half-tile
  const int c0l = (t & 15) * 8;
  const int n0 = n_blk + c0l;
  const int grb0 = m_blk + (L0 >> 5)*64 + (L0 & 31);   // + p*32 per pass

  #pragma unroll
  for (int p = 0; p < 2; ++p){
    __syncthreads();   // protect staging (p=0) / previous pass reads (p=1)
    #pragma unroll
    for (int mt2 = 0; mt2 < 2; ++mt2){
      int lrow = wr*32 + mt2*16 + quad*4;
      #pragma unroll
      for (int nt = 0; nt < 4; ++nt){
        int c = wc*64 + nt*16 + lr;
        #pragma unroll
        for (int i = 0; i < 4; ++i)
          Cf[(lrow+i)*CPAD + c] = acc[2*p+mt2][nt][i];
      }
    }
    __syncthreads();

    epi_vec4(grb0 + p*32, n0, M, mode, bias0, bias1, zb, sb, xw, o0, o1, hO, outF,
             o_start, o_log2, sN, smode, Cf, L0, c0l, CPAD);
  }
}

// ---------------- mid GEMM: 128x64 tile, BK=64, swizzled LDS (for M=2048..8192) ----------------
#define CPAD2 68
__global__ __launch_bounds__(256) void gemm_mid(
    const bf16* __restrict__ A0, const bf16* __restrict__ A1,
    const bf16* __restrict__ Wp, int M, int K, int ldb,
    int a_start, int a_log2, int o_start, int o_log2,
    const float* __restrict__ bias0, const float* __restrict__ bias1,
    const bf16* __restrict__ zb, const bf16* __restrict__ sb,
    const bf16* __restrict__ xw,
    bf16* __restrict__ o0, bf16* __restrict__ o1,
    bf16* __restrict__ hO, float* __restrict__ outF,
    bf16* __restrict__ sN, int smode, int mode)
{
  __shared__ __align__(16) char smemraw[128*CPAD2*4];  // 34.8KB: staging (24KB) U C f32 (34.8KB)
  bf16* As = (bf16*)smemraw;          // 128 x 64
  bf16* Bs = As + 128*64;             // 64 x 64
  float* Cf = (float*)smemraw;        // 128 x CPAD2

  const int t = threadIdx.x, lane = t & 63, wid = t >> 6;
  const int wr = wid >> 1, wc = wid & 1;     // 2 row-waves x 2 col-waves
  const int lr = lane & 15, quad = lane >> 4;

  const int gx = gridDim.x, gy = gridDim.y;
  int nwg = gx * gy;
  int id = blockIdx.y * gx + blockIdx.x;
  int q = nwg >> 3, r8 = nwg & 7;
  int xcd = id & 7, jj = id >> 3;
  int wg = (xcd < r8 ? xcd*(q+1) : r8*(q+1) + (xcd - r8)*q) + jj;
  const int m_blk = (wg / gy) * 128, n_blk = (wg % gy) * 64;

  const int Mm1 = M - 1;
  const int amask = (1 << a_log2) - 1;
  const int wbase = (t & ~63);

  // A staging: 4 chunks/thread (128 rows x 8 chunks of 8)
  const bf16* a0p[4]; const bf16* a1p[4];
  #pragma unroll
  for (int p = 0; p < 4; ++p){
    int c = p*256 + t;
    int rl = c >> 3, slot = c & 7;
    int g = slot ^ (rl & 7);
    int r = m_blk + rl; if (r > Mm1) r = Mm1;
    int tr = r >> a_log2, po = r & amask;
    a0p[p] = A0 + ((size_t)tr*NPT + a_start + po)*FD + g*8;
    a1p[p] = A1 + (size_t)r*FD + g*8;
  }
  // B staging: 2 chunks/thread (64 rows x 8 chunks of 8)
  const bf16* bp[2];
  #pragma unroll
  for (int p = 0; p < 2; ++p){
    int c = p*256 + t;
    int rl = c >> 3, slot = c & 7;
    int g = slot ^ (rl & 7);
    bp[p] = Wp + (size_t)(n_blk + rl)*ldb + g*8;
  }

  f4v acc[4][2] = {};

  for (int k0 = 0; k0 < K; k0 += 64){
    #pragma unroll
    for (int p = 0; p < 4; ++p){
      const bf16* src = (k0 < 512) ? (a0p[p] + k0) : (a1p[p] + (k0 - 512));
      gload_lds16(src, &As[(size_t)(p*256 + wbase)*8]);
    }
    #pragma unroll
    for (int p = 0; p < 2; ++p)
      gload_lds16(bp[p] + k0, &Bs[(size_t)(p*256 + wbase)*8]);
    __syncthreads();

    #pragma unroll
    for (int kh = 0; kh < 2; ++kh){
      int cidx = kh*4 + quad;
      bf8v af[4], bv[2];
      #pragma unroll
      for (int i = 0; i < 4; ++i){
        int ra = wr*64 + i*16 + lr;
        af[i] = *(const bf8v*)&As[ra*64 + ((cidx ^ (ra & 7))*8)];
      }
      #pragma unroll
      for (int j = 0; j < 2; ++j){
        int rb = wc*32 + j*16 + lr;
        bv[j] = *(const bf8v*)&Bs[rb*64 + ((cidx ^ (rb & 7))*8)];
      }
      #pragma unroll
      for (int i = 0; i < 4; ++i)
        #pragma unroll
        for (int j = 0; j < 2; ++j)
          acc[i][j] = __builtin_amdgcn_mfma_f32_16x16x32_bf16(af[i], bv[j], acc[i][j], 0, 0, 0);
    }
    __syncthreads();
  }

  // single-pass spill: 128 x 64 f32 tile
  #pragma unroll
  for (int mt = 0; mt < 4; ++mt){
    int lrow = wr*64 + mt*16 + quad*4;
    #pragma unroll
    for (int nt = 0; nt < 2; ++nt){
      int c = wc*32 + nt*16 + lr;
      #pragma unroll
      for (int i = 0; i < 4; ++i)
        Cf[(lrow+i)*CPAD2 + c] = acc[mt][nt][i];
    }
  }
  __syncthreads();

  // read: thread owns 4 consecutive rows x 8 consecutive cols (256 x 32 = 8192 elems)
  const int L0 = (t >> 3) * 4;       // 0..124
  const int c0l = (t & 7) * 8;       // 0..56
  epi_vec4(m_blk + L0, n_blk + c0l, M, mode, bias0, bias1, zb, sb, xw, o0, o1, hO, outF,
           o_start, o_log2, sN, smode, Cf, L0, c0l, CPAD2);
}

// ---------------- small GEMM: 64x64 tile, direct loads, no barriers ----------------
// K-loop split into A0/A1 regions (no per-iteration select), unrolled.
__global__ __launch_bounds__(256) void gemm_small(
    const bf16* __restrict__ A0, const bf16* __restrict__ A1,
    const bf16* __restrict__ Wp, int M, int K, int ldb,
    int a_start, int a_log2, int o_start, int o_log2,
    const float* __restrict__ bias0, const float* __restrict__ bias1,
    const bf16* __restrict__ zb, const bf16* __restrict__ sb,
    const bf16* __restrict__ xw,
    bf16* __restrict__ o0, bf16* __restrict__ o1,
    bf16* __restrict__ hO, float* __restrict__ outF,
    bf16* __restrict__ sN, int smode, int mode)
{
  const int lane = threadIdx.x & 63, wid = threadIdx.x >> 6;
  const int wr = wid >> 1, wc = wid & 1;
  const int m_base = blockIdx.x*64 + wr*32;
  const int n_base = blockIdx.y*64 + wc*32;
  const int lr = lane & 15, quad = lane >> 4;
  const int Mm1 = M - 1;
  const int amask = (1 << a_log2) - 1;

  f4v acc[2][2] = {};

  const bf16 *a0p[2], *a1p[2], *bp[2];
  #pragma unroll
  for (int mt = 0; mt < 2; ++mt){
    int m = m_base + mt*16 + lr; if (m > Mm1) m = Mm1;
    int tr = m >> a_log2, po = m & amask;
    a0p[mt] = A0 + ((size_t)tr*NPT + a_start + po)*FD + quad*8;
    a1p[mt] = A1 + (size_t)m*FD + quad*8;
  }
  #pragma unroll
  for (int nt = 0; nt < 2; ++nt)
    bp[nt] = Wp + (size_t)(n_base + nt*16 + lr)*ldb + quad*8;

  const int K1 = K < 512 ? K : 512;
  #pragma unroll 8
  for (int k0 = 0; k0 < K1; k0 += 32){
    bf8v a[2], b[2];
    a[0] = *(const bf8v*)(a0p[0] + k0);
    a[1] = *(const bf8v*)(a0p[1] + k0);
    b[0] = *(const bf8v*)(bp[0] + k0);
    b[1] = *(const bf8v*)(bp[1] + k0);
    #pragma unroll
    for (int mt = 0; mt < 2; ++mt)
      #pragma unroll
      for (int nt = 0; nt < 2; ++nt)
        acc[mt][nt] = __builtin_amdgcn_mfma_f32_16x16x32_bf16(a[mt], b[nt], acc[mt][nt], 0, 0, 0);
  }
  #pragma unroll 8
  for (int k0 = 512; k0 < K; k0 += 32){
    bf8v a[2], b[2];
    a[0] = *(const bf8v*)(a1p[0] + (k0 - 512));
    a[1] = *(const bf8v*)(a1p[1] + (k0 - 512));
    b[0] = *(const bf8v*)(bp[0] + k0);
    b[1] = *(const bf8v*)(bp[1] + k0);
    #pragma unroll
    for (int mt = 0; mt < 2; ++mt)
      #pragma unroll
      for (int nt = 0; nt < 2; ++nt)
        acc[mt][nt] = __builtin_amdgcn_mfma_f32_16x16x32_bf16(a[mt], b[nt], acc[mt][nt], 0, 0, 0);
  }

  #pragma unroll
  for (int mt = 0; mt < 2; ++mt){
    int rbase = m_base + mt*16 + quad*4;
    #pragma unroll
    for (int nt = 0; nt < 2; ++nt){
      int n = n_base + nt*16 + lr;
      epi4(acc[mt][nt], rbase, n, M, mode, bias0, bias1, zb, sb, xw, o0, o1, hO, outF,
           o_start, o_log2, sN, smode);
    }
  }
}

// ---------------- host launcher ----------------

extern "C" void kernel_launch(void* const* d_in, const int* in_sizes, int n_in,
                              void* d_out, int out_size, void* d_ws, size_t ws_size,
                              hipStream_t stream)
{
  const float* feat = (const float*)d_in[0];
  const float* Wh   = (const float*)d_in[1];
  const float* Wz   = (const float*)d_in[2];
  const float* Wr   = (const float*)d_in[3];
  const float* Uh   = (const float*)d_in[4];
  const float* Uz   = (const float*)d_in[5];
  const float* bUz  = (const float*)d_in[6];
  const float* Ur   = (const float*)d_in[7];
  const float* bUr  = (const float*)d_in[8];
  const float* Whd  = (const float*)d_in[9];
  const float* Wzd  = (const float*)d_in[10];
  const float* Wrd  = (const float*)d_in[11];
  const float* Uhd  = (const float*)d_in[12];
  const float* Uzd  = (const float*)d_in[13];
  const float* bUzd = (const float*)d_in[14];
  const float* Urd  = (const float*)d_in[15];
  const float* bUrd = (const float*)d_in[16];
  const float* W1   = (const float*)d_in[17];
  const float* b1   = (const float*)d_in[18];
  const float* W2   = (const float*)d_in[19];
  const float* b2   = (const float*)d_in[20];
  float* out = (float*)d_out;

  int starts[12], szs[12];
  { int s = 0, sz = 2048; for (int l = 0; l < 12; ++l){ starts[l] = s; szs[l] = sz; s += sz; sz >>= 1; } }

  char* p = (char*)d_ws;
  auto take = [&](size_t b)->char*{ char* q = p; p += (b + 255) & ~(size_t)255; return q; };
  bf16* featb = (bf16*)take((size_t)NT*FD*2);
  bf16* h_b   = (bf16*)take((size_t)NT*FD*2);
  bf16* hd_b  = (bf16*)take((size_t)NT*FD*2);
  bf16* Wzr_u = (bf16*)take((size_t)1024*512*2);
  bf16* Wzr_d = (bf16*)take((size_t)1024*512*2);
  bf16* Uzr_u = (bf16*)take((size_t)1024*512*2);
  bf16* Uzr_d = (bf16*)take((size_t)1024*512*2);
  bf16* Whu   = (bf16*)take((size_t)512*1024*2);
  bf16* Whu_d = (bf16*)take((size_t)512*1024*2);
  bf16* Wout  = (bf16*)take((size_t)512*1024*2);
  bf16* z16   = (bf16*)take((size_t)16384*512*2);
  bf16* rh16  = (bf16*)take((size_t)16384*512*2);
  bf16* sP0   = (bf16*)take((size_t)16384*512*2);
  bf16* sP1   = (bf16*)take((size_t)16384*512*2);
  if ((size_t)(p - (char*)d_ws) > ws_size) return;

  // xWzr = per-node x@[Wz|Wr] (NT x 1024 bf16) lives in d_out as scratch
  bf16* xWzr = (bf16*)d_out;

  // --- stage inputs: 2 launches ---
  cvt_b16<<<(NT*FD/8 + 255)/256, 256, 0, stream>>>(featb, feat, NT*FD/8);
  PackArgs pa;
  int pi = 0;
  auto pk = [&](const float* src, bf16* dst, int dk, int ro, int co){
    pa.s[pi] = src; pa.d[pi] = dst; pa.dk[pi] = dk; pa.ro[pi] = ro; pa.co[pi] = co; ++pi;
  };
  pk(Wz, Wzr_u, 512, 0, 0);    pk(Wr, Wzr_u, 512, 512, 0);
  pk(Wzd, Wzr_d, 512, 0, 0);   pk(Wrd, Wzr_d, 512, 512, 0);
  pk(Uz, Uzr_u, 512, 0, 0);    pk(Ur, Uzr_u, 512, 512, 0);
  pk(Uzd, Uzr_d, 512, 0, 0);   pk(Urd, Uzr_d, 512, 512, 0);
  pk(Wh, Whu, 1024, 0, 0);     pk(Uh, Whu, 1024, 0, 512);
  pk(Whd, Whu_d, 1024, 0, 0);  pk(Uhd, Whu_d, 1024, 0, 512);
  pk(W1, Wout, 1024, 0, 0);    pk(W2, Wout, 1024, 0, 512);
  pack_all<<<14*128, 256, 0, stream>>>(pa);

  auto gemm = [&](const bf16* A0, const bf16* A1, const bf16* Wp, int M, int N, int K, int ldb,
                  int a_start, int a_log2, int o_start, int o_log2,
                  const float* bias0, const float* bias1,
                  const bf16* zb, const bf16* sb, const bf16* xw,
                  bf16* o0, bf16* o1, bf16* hO, float* outF,
                  bf16* sN, int smode, int mode){
    if (M >= 16384){
      dim3 g((M + 127)/128, N/128);
      gemm_big<<<g, 256, 0, stream>>>(A0, A1, Wp, M, K, ldb, a_start, a_log2, o_start, o_log2,
                                      bias0, bias1, zb, sb, xw, o0, o1, hO, outF, sN, smode, mode);
    } else if (M >= 2048){
      dim3 g((M + 127)/128, N/64);
      gemm_mid<<<g, 256, 0, stream>>>(A0, A1, Wp, M, K, ldb, a_start, a_log2, o_start, o_log2,
                                      bias0, bias1, zb, sb, xw, o0, o1, hO, outF, sN, smode, mode);
    } else {
      dim3 g((M + 63)/64, N/64);
      gemm_small<<<g, 256, 0, stream>>>(A0, A1, Wp, M, K, ldb, a_start, a_log2, o_start, o_log2,
                                        bias0, bias1, zb, sb, xw, o0, o1, hO, outF, sN, smode, mode);
    }
  };

  // --- precompute-up: xWzr[node] = x@[Wz|Wr] for ALL nodes ---
  gemm(featb, featb, Wzr_u, NT, 1024, 512, 512, 0, 26, 0, 26,
       nullptr, nullptr, nullptr, nullptr, nullptr, xWzr, nullptr, nullptr, nullptr, nullptr, 0, 3);

  // --- leaves fused: h = (1-sig(xWzr_z))*tanh(x@Wh); pair-sum -> sP0 (mode 5) ---
  gemm(featb, featb, Whu, 16384, 512, 512, 1024, 0, 11, 0, 11,
       nullptr, nullptr, nullptr, nullptr, xWzr, nullptr, nullptr, h_b, nullptr, sP0, 1, 5);

  // --- bottom-up ---
  for (int l = 0; l < 11; ++l){
    int Mf = 8*szs[l+1];
    int al2 = 10 - l, os = starts[l+1];
    bf16* sCur = (l & 1) ? sP1 : sP0;
    bf16* sNext = (l & 1) ? sP0 : sP1;
    int smode = (l < 10) ? 1 : 0;
    gemm(sCur, sCur, Uzr_u, Mf, 1024, 512, 512, 0, 26, os, al2,
         bUz, bUr, nullptr, sCur, xWzr, z16, rh16, nullptr, nullptr, nullptr, 0, 1);
    gemm(featb, rh16, Whu, Mf, 512, 1024, 1024, os, al2, os, al2,
         nullptr, nullptr, z16, sCur, nullptr, nullptr, nullptr, h_b, nullptr, sNext, smode, 2);
  }

  // --- precompute-down: xWzr[node] = x@[Wzd|Wrd] ---
  gemm(featb, featb, Wzr_d, NT, 1024, 512, 512, 0, 26, 0, 26,
       nullptr, nullptr, nullptr, nullptr, nullptr, xWzr, nullptr, nullptr, nullptr, nullptr, 0, 3);

  // --- roots ---
  roots_k<<<2, 256, 0, stream>>>(hd_b, sP0, h_b);

  // --- top-down ---
  for (int l = 10; l >= 0; --l){
    int Ms = 8*szs[l];
    int al2 = 11 - l, os = starts[l];
    bf16* sCur = ((10 - l) & 1) ? sP1 : sP0;
    bf16* sNext = ((10 - l) & 1) ? sP0 : sP1;
    int smode = (l > 0) ? 2 : 0;
    gemm(sCur, sCur, Uzr_d, Ms, 1024, 512, 512, 0, 26, os, al2,
         bUzd, bUrd, nullptr, sCur, xWzr, z16, rh16, nullptr, nullptr, nullptr, 0, 1);
    gemm(featb, rh16, Whu_d, Ms, 512, 1024, 1024, os, al2, os, al2,
         nullptr, nullptr, z16, sCur, nullptr, nullptr, nullptr, hd_b, nullptr, sNext, smode, 2);
  }

  // --- output: [h|hd] @ [W1|W2].T + b1 + b2 ---
  gemm(h_b, hd_b, Wout, NT, 512, 1024, 1024, 0, 26, 0, 26,
       b1, b2, nullptr, nullptr, nullptr, nullptr, nullptr, nullptr, out, nullptr, 0, 4);
}